// Round 17
// baseline (657.410 us; speedup 1.0000x reference)
//
#include <hip/hip_runtime.h>
#include <cstdint>
#include <cstddef>

typedef __bf16 bf16;
typedef __bf16 bf16x2 __attribute__((ext_vector_type(2)));
typedef __bf16 bf16x4 __attribute__((ext_vector_type(4)));
typedef __bf16 bf16x8 __attribute__((ext_vector_type(8)));
typedef float f32x4 __attribute__((ext_vector_type(4)));
typedef unsigned int u32x4 __attribute__((ext_vector_type(4)));

#define S_TOK 3520
#define S_PAD 3584
#define P_TOK 880
#define NFRM 4
#define DIM 1536
#define NH 12
#define HD 128
#define FFN_D 6144
#define NOUT 64
#define EPSV 1e-6f
#define QSCALE 0.12751743f   /* log2(e)/sqrt(128) */

__device__ __forceinline__ f32x4 mfma16(bf16x8 a, bf16x8 b, f32x4 c) {
  return __builtin_amdgcn_mfma_f32_16x16x32_bf16(a, b, c, 0, 0, 0);
}

__device__ __forceinline__ void gload_lds16(const bf16* g, bf16* l) {
  __builtin_amdgcn_global_load_lds(
      (const __attribute__((address_space(1))) unsigned int*)g,
      (__attribute__((address_space(3))) unsigned int*)l, 16, 0, 0);
}

__device__ __forceinline__ uint32_t pk2(float lo, float hi) {
  bf16x2 t;
  t[0] = (bf16)lo;
  t[1] = (bf16)hi;
  return __builtin_bit_cast(uint32_t, t);
}

// ---------------- prep: em = mod_block + e ; ehm = mod_head + e_head ----------------
__global__ __launch_bounds__(256) void k_prep(const float* __restrict__ e,
                                              const float* __restrict__ e_head,
                                              const float* __restrict__ mod_block,
                                              const float* __restrict__ mod_head,
                                              float* __restrict__ em,
                                              float* __restrict__ ehm) {
  int i = blockIdx.x * 256 + threadIdx.x;
  if (i < NFRM * 6 * DIM) em[i] = mod_block[i % (6 * DIM)] + e[i];
  int j = i - NFRM * 6 * DIM;
  if (j >= 0 && j < NFRM * 2 * DIM) ehm[j] = mod_head[j % (2 * DIM)] + e_head[j];
}

// ---------------- trig table: cstab[s*64+c] = {cos, sin}(ang[s][c]) ----------------
__global__ __launch_bounds__(256) void k_trig(const float* __restrict__ ang,
                                              float* __restrict__ cstab) {
  int idx = blockIdx.x * 256 + threadIdx.x;  // 880 blocks * 256 = 225280 = 3520*64
  float a = ang[idx];
  float sa, ca;
  sincosf(a, &sa, &ca);
  cstab[2 * idx] = ca;
  cstab[2 * idx + 1] = sa;
}

// ---------------- zero the V-chunk frame-tail pad (lb=27, slots 256..511) ----------------
__global__ __launch_bounds__(256) void k_zero_vpad(bf16* __restrict__ vc) {
  size_t base = ((size_t)blockIdx.x * 28 + 27) * 4096 + 2048 + (size_t)threadIdx.x * 8;
#pragma unroll
  for (int i = 0; i < 8; ++i) vc[base + i] = (bf16)0.f;
}

// ---------------- transpose f32 [K][N] -> bf16 [N][K] ----------------
__global__ __launch_bounds__(256) void k_transpose(const float* __restrict__ W,
                                                   bf16* __restrict__ Wt, int K, int N) {
  __shared__ float tile[32][33];
  int n0 = blockIdx.x * 32, k0 = blockIdx.y * 32;
  int tx = threadIdx.x & 31, ty = threadIdx.x >> 5;  // ty 0..7
#pragma unroll
  for (int j = 0; j < 4; ++j) {
    int k = k0 + ty * 4 + j;
    float v = (n0 + tx < N) ? W[(size_t)k * N + n0 + tx] : 0.f;
    tile[ty * 4 + j][tx] = v;
  }
  __syncthreads();
#pragma unroll
  for (int j = 0; j < 4; ++j) {
    int n = n0 + ty * 4 + j;
    if (n < N) Wt[(size_t)n * K + k0 + tx] = (bf16)tile[tx][ty * 4 + j];
  }
}

// ---------------- AdaLN: out_bf16 = LN(in)*(1+scale[f]) + shift[f]; pad rows -> 0 ----------------
__global__ __launch_bounds__(256) void k_adaln(const float* __restrict__ in,
                                               bf16* __restrict__ out,
                                               const float* __restrict__ e_shift,
                                               const float* __restrict__ e_scale,
                                               int fstride) {
  int tok = blockIdx.x;
  int t = threadIdx.x;
  bf16* orow = out + (size_t)tok * DIM;
  if (tok >= S_TOK) {
#pragma unroll
    for (int i = 0; i < 6; ++i) orow[t * 6 + i] = (bf16)0.f;
    return;
  }
  const float* xrow = in + (size_t)tok * DIM;
  float v[6];
  float s = 0.f, sq = 0.f;
#pragma unroll
  for (int i = 0; i < 6; ++i) {
    v[i] = xrow[t * 6 + i];
    s += v[i];
    sq += v[i] * v[i];
  }
  for (int off = 32; off; off >>= 1) {
    s += __shfl_down(s, off);
    sq += __shfl_down(sq, off);
  }
  __shared__ float red[8];
  int wv = t >> 6, lane = t & 63;
  if (lane == 0) { red[wv] = s; red[4 + wv] = sq; }
  __syncthreads();
  float ts = red[0] + red[1] + red[2] + red[3];
  float tq = red[4] + red[5] + red[6] + red[7];
  float mean = ts * (1.f / DIM);
  float var = tq * (1.f / DIM) - mean * mean;
  float rstd = rsqrtf(var + EPSV);
  int f = tok / P_TOK;
  const float* sh = e_shift + (size_t)f * fstride;
  const float* sc = e_scale + (size_t)f * fstride;
#pragma unroll
  for (int i = 0; i < 6; ++i) {
    int d = t * 6 + i;
    orow[d] = (bf16)((v[i] - mean) * rstd * (1.f + sc[d]) + sh[d]);
  }
}

// ---------------- QKV postproc (bf16 in): RMSNorm(q,k) + RoPE (table), scale q; v -> chunked ----------------
__global__ __launch_bounds__(256) void k_qkv_post(const bf16* __restrict__ qkv,
                                                  const float* __restrict__ wqn,
                                                  const float* __restrict__ wkn,
                                                  const float* __restrict__ cstab,
                                                  bf16* __restrict__ qb,
                                                  bf16* __restrict__ kb,
                                                  bf16* __restrict__ vc) {
  int s = blockIdx.x;
  int t = threadIdx.x;
  const bf16* row = qkv + (size_t)s * 3 * DIM;
  float qv[6], kv[6], vv[6];
  float sqq = 0.f, sqk = 0.f;
  int d0 = t * 6;
#pragma unroll
  for (int i = 0; i < 6; ++i) {
    int d = d0 + i;
    qv[i] = (float)row[d];
    kv[i] = (float)row[DIM + d];
    vv[i] = (float)row[2 * DIM + d];
    sqq += qv[i] * qv[i];
    sqk += kv[i] * kv[i];
  }
  float a1 = sqq, a2 = sqk;
  for (int off = 32; off; off >>= 1) {
    a1 += __shfl_down(a1, off);
    a2 += __shfl_down(a2, off);
  }
  __shared__ float red[8];
  int wv = t >> 6, lane = t & 63;
  if (lane == 0) { red[wv] = a1; red[4 + wv] = a2; }
  __syncthreads();
  float tq = red[0] + red[1] + red[2] + red[3];
  float tk = red[4] + red[5] + red[6] + red[7];
  float rq = rsqrtf(tq * (1.f / DIM) + EPSV);
  float rk = rsqrtf(tk * (1.f / DIM) + EPSV);
  const float2* cs2 = (const float2*)cstab + (size_t)s * 64;
#pragma unroll
  for (int p = 0; p < 3; ++p) {
    int d = d0 + p * 2;
    int h = d >> 7;
    int hd = d & 127;
    int c = hd >> 1;
    float2 cs = cs2[c];
    float ca = cs.x, sa = cs.y;
    float q0 = qv[p * 2] * rq * wqn[d], q1 = qv[p * 2 + 1] * rq * wqn[d + 1];
    float k0 = kv[p * 2] * rk * wkn[d], k1 = kv[p * 2 + 1] * rk * wkn[d + 1];
    size_t base = ((size_t)h * S_TOK + s) * HD + hd;
    qb[base]     = (bf16)((q0 * ca - q1 * sa) * QSCALE);
    qb[base + 1] = (bf16)((q0 * sa + q1 * ca) * QSCALE);
    kb[base]     = (bf16)(k0 * ca - k1 * sa);
    kb[base + 1] = (bf16)(k0 * sa + k1 * ca);
  }
  int f = s / P_TOK;
  int l = s - f * P_TOK;
  int lb = l >> 5, gg = (l >> 3) & 3, r = l & 7;
#pragma unroll
  for (int i = 0; i < 6; ++i) {
    int d = d0 + i;
    int h = d >> 7, hd = d & 127;
    vc[((((size_t)(h * NFRM + f)) * 28 + lb) * 512 + gg * 128 + hd) * 8 + r] = (bf16)vv[i];
  }
}

// ---------------- attention (split-KV partials), KVBLK=32, dbuf-K + single-buffer V (24KB LDS) ----------------
// V is consumed only at the END of each step, so V(j)'s staging (issued at step start, after
// the WAR barrier of step j-1) has the whole QK+softmax phase to land -> single buffer.
// LDS 24KB -> 6 blocks/CU (30 waves, was 25). Ledger: iter j issues V(j) + K(j+1); vmcnt(4)
// leaves only K(j+1) in flight => K(j) (issued iter j-1) and V(j) complete. barrier2 protects
// Vs and Ks[(j+1)&1] reads before overwrite.
__global__ __launch_bounds__(320) void k_attn(const bf16* __restrict__ qb,
                                              const bf16* __restrict__ kb,
                                              const bf16* __restrict__ vc,
                                              bf16* __restrict__ parto,
                                              float* __restrict__ partml) {
  __shared__ __align__(16) bf16 Ks[2][512 * 8];
  __shared__ __align__(16) bf16 Vs[512 * 8];
  int h = blockIdx.x / 110;
  int p = blockIdx.x % 110;
  int f = (p < 11) ? 0 : (p < 33) ? 1 : (p < 66) ? 2 : 3;
  int cum = (f == 0) ? 0 : (f == 1) ? 11 : (f == 2) ? 33 : 66;
  int w = p - cum;
  int kc = w / 11;
  int qt = f * 11 + w % 11;
  int slot = blockIdx.x;
  int t = threadIdx.x;
  int wv = t >> 6, lane = t & 63;
  int r16 = lane & 15, g = lane >> 4;
  int q0 = qt * 80 + wv * 16;
  int kv0 = kc * P_TOK;
  const bf16* qbase = qb + ((size_t)h * S_TOK + q0 + r16) * HD + g * 8;
  bf16x8 qf[4];
#pragma unroll
  for (int kk = 0; kk < 4; ++kk) qf[kk] = *(const bf16x8*)(qbase + kk * 32);
  f32x4 acc[8] = {};
  float mrow = -1e30f, lrow = 0.f;
  int src01 = r16 + ((2 * g) & 3) * 16;
  int src23 = src01 + 16;
  bool glo = (g < 2);
  int sB = t + 256;
  int kr0 = t >> 4, kl0 = t & 15;
  int ks0 = (kl0 & 8) | ((kl0 ^ kr0) & 7);
  int kr1 = sB >> 4, kl1 = sB & 15;
  int ks1 = (kl1 & 8) | ((kl1 ^ kr1) & 7);
  const bf16* kh = kb + (size_t)h * S_TOK * HD;
  const bf16* vchunk = vc + ((size_t)(h * NFRM + kc)) * 28 * 4096;
#define STAGE_K(buf, jj)                                                    \
  do {                                                                      \
    int kvoj = (jj) * 32;                                                   \
    int gr0 = kv0 + kvoj + kr0; if (gr0 >= S_TOK) gr0 = 0;                  \
    int gr1 = kv0 + kvoj + kr1; if (gr1 >= S_TOK) gr1 = 0;                  \
    gload_lds16(kh + (size_t)gr0 * HD + ks0 * 8, Ks[buf] + t * 8);          \
    gload_lds16(kh + (size_t)gr1 * HD + ks1 * 8, Ks[buf] + sB * 8);         \
  } while (0)
#define STAGE_V(jj)                                                         \
  do {                                                                      \
    gload_lds16(vchunk + (size_t)(jj) * 4096 + t * 8, Vs + t * 8);          \
    gload_lds16(vchunk + (size_t)(jj) * 4096 + sB * 8, Vs + sB * 8);        \
  } while (0)
  const int nsteps = (P_TOK + 31) >> 5;  // 28; last step half-masked (880 = 27*32+16)
  if (t < 256) STAGE_K(0, 0);
  int vrb = g * 128 + r16;
  for (int j = 0; j < nsteps; ++j) {
    if (t < 256) STAGE_V(j);
    if (j + 1 < nsteps) {
      if (t < 256) STAGE_K((j + 1) & 1, j + 1);
      asm volatile("s_waitcnt vmcnt(4)" ::: "memory");  // K(j), V(j) landed; K(j+1) in flight
    } else {
      asm volatile("s_waitcnt vmcnt(0)" ::: "memory");
    }
    __builtin_amdgcn_s_barrier();  // cur K/V valid for all waves
    const bf16* Kc = Ks[j & 1];
    f32x4 st0 = {0.f, 0.f, 0.f, 0.f}, st1 = {0.f, 0.f, 0.f, 0.f};
#pragma unroll
    for (int kk = 0; kk < 4; ++kk) {
      int sl = g + 4 * kk;
      int ss = (sl & 8) | ((sl ^ r16) & 7);
      bf16x8 k0 = *(const bf16x8*)(Kc + (r16 * 16 + ss) * 8);
      bf16x8 k1 = *(const bf16x8*)(Kc + ((16 + r16) * 16 + ss) * 8);
      st0 = mfma16(k0, qf[kk], st0);
      st1 = mfma16(k1, qf[kk], st1);
    }
    float hm = (j == nsteps - 1) ? -1e30f : 0.f;
    float a0[4], a1[4];
#pragma unroll
    for (int r = 0; r < 4; ++r) {
      a0[r] = st0[r];
      a1[r] = st1[r] + hm;
    }
    float tm = fmaxf(fmaxf(fmaxf(a0[0], a0[1]), fmaxf(a0[2], a0[3])),
                     fmaxf(fmaxf(a1[0], a1[1]), fmaxf(a1[2], a1[3])));
    tm = fmaxf(tm, __shfl_xor(tm, 16));
    tm = fmaxf(tm, __shfl_xor(tm, 32));
    // T13 defer-max
    bool defer = __all(tm <= mrow + 8.f);
    if (!defer) {
      float mn = fmaxf(mrow, tm);
      float scl = exp2f(mrow - mn);
      lrow *= scl;
#pragma unroll
      for (int hb = 0; hb < 8; ++hb) {
        acc[hb][0] *= scl;
        acc[hb][1] *= scl;
        acc[hb][2] *= scl;
        acc[hb][3] *= scl;
      }
      mrow = mn;
    }
    float p0[4], p1[4], ps = 0.f;
#pragma unroll
    for (int r = 0; r < 4; ++r) {
      p0[r] = exp2f(a0[r] - mrow);
      p1[r] = exp2f(a1[r] - mrow);
      ps += p0[r] + p1[r];
    }
    lrow += ps;
    uint32_t A0 = pk2(p0[0], p0[1]), A1 = pk2(p0[2], p0[3]);
    uint32_t B0 = pk2(p1[0], p1[1]), B1 = pk2(p1[2], p1[3]);
    uint32_t sA0 = __shfl(A0, src01), sA1 = __shfl(A1, src01);
    uint32_t sB0 = __shfl(B0, src01), sB1 = __shfl(B1, src01);
    uint32_t tA0 = __shfl(A0, src23), tA1 = __shfl(A1, src23);
    uint32_t tB0 = __shfl(B0, src23), tB1 = __shfl(B1, src23);
    u32x4 wds;
    wds[0] = glo ? sA0 : sB0;
    wds[1] = glo ? sA1 : sB1;
    wds[2] = glo ? tA0 : tB0;
    wds[3] = glo ? tA1 : tB1;
    bf16x8 pb = __builtin_bit_cast(bf16x8, wds);
    const bf16* vsl = Vs + (size_t)vrb * 8;
#pragma unroll
    for (int hb = 0; hb < 8; ++hb) {
      bf16x8 vfr = *(const bf16x8*)(vsl + hb * 128);
      acc[hb] = mfma16(vfr, pb, acc[hb]);
    }
    asm volatile("" ::: "memory");
    __builtin_amdgcn_s_barrier();  // all waves done reading Vs + Ks[j&1] -> next iter may overwrite
  }
#undef STAGE_K
#undef STAGE_V
  lrow += __shfl_xor(lrow, 16);
  lrow += __shfl_xor(lrow, 32);
  // bf16 O-partials (element stride 2048/wave):
  bf16* obase = parto + ((size_t)slot * 5 + wv) * 2048;
#pragma unroll
  for (int hb = 0; hb < 8; ++hb) {
    bf16x4 ov;
    ov[0] = (bf16)acc[hb][0];
    ov[1] = (bf16)acc[hb][1];
    ov[2] = (bf16)acc[hb][2];
    ov[3] = (bf16)acc[hb][3];
    *(bf16x4*)(obase + (hb * 64 + lane) * 4) = ov;
  }
  if (g == 0) {
    float* mlb = partml + ((size_t)slot * 5 + wv) * 32;
    mlb[r16] = mrow;
    mlb[16 + r16] = lrow;
  }
}

// ---------------- attention reduce: combine <=4 frame-chunk partials per q-row ----------------
__global__ __launch_bounds__(256) void k_att_reduce(const bf16* __restrict__ parto,
                                                    const float* __restrict__ partml,
                                                    bf16* __restrict__ attb) {
  int b = blockIdx.x;
  int h = b / 44, qt = b % 44;
  int f = qt / 11, j = qt % 11;
  int cum = (f == 0) ? 0 : (f == 1) ? 11 : (f == 2) ? 33 : 66;
  int t = threadIdx.x;
  int d = t & 127, half = t >> 7;
  int hb = d >> 4, g = (d >> 2) & 3, r = d & 3;
  int q0 = qt * 80;
  for (int it = 0; it < 40; ++it) {
    int qloc = it + 40 * half;
    int wv = qloc >> 4, r16 = qloc & 15;
    float m[4], l[4];
    float mt = -1e30f;
    for (int kc = 0; kc <= f; ++kc) {
      int slot = h * 110 + cum + kc * 11 + j;
      const float* mlb = partml + ((size_t)slot * 5 + wv) * 32;
      m[kc] = mlb[r16];
      l[kc] = mlb[16 + r16];
      mt = fmaxf(mt, m[kc]);
    }
    float lt = 0.f, o = 0.f;
    for (int kc = 0; kc <= f; ++kc) {
      int slot = h * 110 + cum + kc * 11 + j;
      float wgt = exp2f(m[kc] - mt);
      lt += l[kc] * wgt;
      o += (float)parto[(((size_t)slot * 5 + wv) * 8 + hb) * 256 + (g * 16 + r16) * 4 + r] * wgt;
    }
    attb[(size_t)(q0 + qloc) * DIM + h * HD + d] = (bf16)(o / lt);
  }
}

// ---------------- unified 128x128 BK=64 GEMM (R14 exact): 8 waves, 2 blocks/CU, counted vmcnt ----------------
struct GemmP {
  const bf16* A;
  const bf16* Bt;
  int K;
  int Mtiles;
  int Ntiles;
  int Mreal;
  int mode;  // 0: qkv bias3 -> bf16  1: res + (acc+b)*emod  2: gelu->bf16  4: head (col<64)
  const float* bias0;
  const float* bias1;
  const float* bias2;
  const float* res;
  const float* emod;
  int e_fstride;
  float* outf;
  bf16* outb;
  int ldo;
};

__global__ __launch_bounds__(512, 4) void k_gemm(GemmP p) {
  // bijective XCD-chunked swizzle (m204), column-major (bm-fast) within chunk
  int nwg = p.Mtiles * p.Ntiles;
  int bid = blockIdx.x;
  int xq = nwg >> 3, xr = nwg & 7;
  int xcd = bid & 7, jj = bid >> 3;
  int wg = (xcd < xr ? xcd * (xq + 1) : xr * (xq + 1) + (xcd - xr) * xq) + jj;
  int bm = wg % p.Mtiles;
  int bn = wg / p.Mtiles;
  __shared__ __align__(16) bf16 Asl[2][128 * 64];
  __shared__ __align__(16) bf16 Bsl[2][128 * 64];
  int t = threadIdx.x, lane = t & 63, wv = t >> 6;
  int r16 = lane & 15, g = lane >> 4;
  int s7 = r16 & 7;
  int wr = wv >> 2, wc = wv & 3;  // 2 x 4 wave grid; wave tile = 64 x 32
  f32x4 acc[4][2] = {};
  const bf16* Ag = p.A + (size_t)bm * 128 * p.K;
  const bf16* Bg = p.Bt + (size_t)bn * 128 * p.K;
  int b0 = t, b1 = t + 512;
  int rw0 = b0 >> 3, cb0 = (b0 & 7) ^ (rw0 & 7);
  int rw1 = b1 >> 3, cb1 = (b1 & 7) ^ (rw1 & 7);
#define STAGE(d, kt)                                                          \
  do {                                                                        \
    int k0s = (kt) * 64;                                                      \
    gload_lds16(Ag + (size_t)rw0 * p.K + k0s + cb0 * 8, Asl[d] + b0 * 8);     \
    gload_lds16(Ag + (size_t)rw1 * p.K + k0s + cb1 * 8, Asl[d] + b1 * 8);     \
    gload_lds16(Bg + (size_t)rw0 * p.K + k0s + cb0 * 8, Bsl[d] + b0 * 8);     \
    gload_lds16(Bg + (size_t)rw1 * p.K + k0s + cb1 * 8, Bsl[d] + b1 * 8);     \
  } while (0)
  const int nt = p.K >> 6;
  STAGE(0, 0);
  int cur = 0;
  for (int tt = 0; tt < nt; ++tt) {
    if (tt + 1 < nt) {
      STAGE(cur ^ 1, tt + 1);
      asm volatile("s_waitcnt vmcnt(4)" ::: "memory");  // cur's 4 loads (1 K-step old) done
    } else {
      asm volatile("s_waitcnt vmcnt(0)" ::: "memory");
    }
    __builtin_amdgcn_s_barrier();  // cur tile visible to all waves
    bf16x8 af[4][2], bfr[2][2];
#pragma unroll
    for (int mi = 0; mi < 4; ++mi)
#pragma unroll
      for (int kk = 0; kk < 2; ++kk)
        af[mi][kk] = *(const bf16x8*)(Asl[cur] + (size_t)(wr * 64 + mi * 16 + r16) * 64 +
                                      (((kk * 4 + g) ^ s7) * 8));
#pragma unroll
    for (int ni = 0; ni < 2; ++ni)
#pragma unroll
      for (int kk = 0; kk < 2; ++kk)
        bfr[ni][kk] = *(const bf16x8*)(Bsl[cur] + (size_t)(wc * 32 + ni * 16 + r16) * 64 +
                                       (((kk * 4 + g) ^ s7) * 8));
    __builtin_amdgcn_s_setprio(1);
#pragma unroll
    for (int mi = 0; mi < 4; ++mi)
#pragma unroll
      for (int ni = 0; ni < 2; ++ni)
#pragma unroll
        for (int kk = 0; kk < 2; ++kk)
          acc[mi][ni] = mfma16(af[mi][kk], bfr[ni][kk], acc[mi][ni]);
    __builtin_amdgcn_s_setprio(0);
    asm volatile("" ::: "memory");
    __builtin_amdgcn_s_barrier();  // all waves done reading cur -> next iter may overwrite
    cur ^= 1;
  }
#undef STAGE
  int mbase = bm * 128 + wr * 64, nbase = bn * 128 + wc * 32;
#pragma unroll
  for (int mi = 0; mi < 4; ++mi) {
#pragma unroll
    for (int ni = 0; ni < 2; ++ni) {
      int col = nbase + ni * 16 + r16;
#pragma unroll
      for (int r = 0; r < 4; ++r) {
        int row = mbase + mi * 16 + 4 * g + r;
        if (row >= p.Mreal) continue;
        float v = acc[mi][ni][r];
        if (p.mode == 0) {
          float b = col < DIM ? p.bias0[col]
                              : (col < 2 * DIM ? p.bias1[col - DIM] : p.bias2[col - 2 * DIM]);
          p.outb[(size_t)row * p.ldo + col] = (bf16)(v + b);
        } else if (p.mode == 1) {
          int fr = row / P_TOK;
          p.outf[(size_t)row * p.ldo + col] =
              p.res[(size_t)row * DIM + col] +
              (v + p.bias0[col]) * p.emod[(size_t)fr * p.e_fstride + col];
        } else if (p.mode == 2) {
          float xg = v + p.bias0[col];
          float gl = 0.5f * xg * (1.f + tanhf(0.7978845608028654f * (xg + 0.044715f * xg * xg * xg)));
          p.outb[(size_t)row * p.ldo + col] = (bf16)gl;
        } else {  // mode 4
          if (col < NOUT) p.outf[(size_t)row * p.ldo + col] = v + p.bias0[col];
        }
      }
    }
  }
}

extern "C" void kernel_launch(void* const* d_in, const int* in_sizes, int n_in,
                              void* d_out, int out_size, void* d_ws, size_t ws_size,
                              hipStream_t stream) {
  const float* x = (const float*)d_in[0];
  const float* e = (const float*)d_in[1];
  const float* e_head = (const float*)d_in[2];
  const float* ang = (const float*)d_in[3];
  const float* mod_block = (const float*)d_in[4];
  const float* mod_head = (const float*)d_in[5];
  const float* Wq = (const float*)d_in[6];
  const float* bq = (const float*)d_in[7];
  const float* Wk = (const float*)d_in[8];
  const float* bk = (const float*)d_in[9];
  const float* Wv = (const float*)d_in[10];
  const float* bv = (const float*)d_in[11];
  const float* Wo = (const float*)d_in[12];
  const float* bo = (const float*)d_in[13];
  const float* wqn = (const float*)d_in[14];
  const float* wkn = (const float*)d_in[15];
  const float* W1 = (const float*)d_in[16];
  const float* b1 = (const float*)d_in[17];
  const float* W2 = (const float*)d_in[18];
  const float* b2 = (const float*)d_in[19];
  const float* Wh = (const float*)d_in[20];
  const float* bh = (const float*)d_in[21];
  float* out = (float*)d_out;
  char* ws = (char*)d_ws;

  size_t WT_QKV = 0;
  size_t WT_O = WT_QKV + (size_t)3 * DIM * DIM * 2;
  size_t W1T = WT_O + (size_t)DIM * DIM * 2;
  size_t W2T = W1T + (size_t)FFN_D * DIM * 2;
  size_t WHT = W2T + (size_t)DIM * FFN_D * 2;
  size_t EMOFF = WHT + (size_t)128 * DIM * 2;
  size_t EHOFF = EMOFF + (size_t)NFRM * 6 * DIM * 4;
  size_t HB = EHOFF + (size_t)NFRM * 2 * DIM * 4;
  size_t CQKV = HB + (size_t)S_PAD * DIM * 2;
  size_t DQB = CQKV + (size_t)S_TOK * 3 * DIM * 4;
  size_t EATT = DQB + (size_t)3 * NH * S_TOK * HD * 2;
  size_t GXF2 = EATT + (size_t)S_PAD * DIM * 2;
  size_t TRIG = GXF2 + (size_t)S_TOK * DIM * 4;
  size_t END = TRIG + (size_t)S_TOK * 64 * 2 * 4;
  if (ws_size < END) return;  // insufficient workspace: bail cleanly

  bf16* wtqkv = (bf16*)(ws + WT_QKV);
  bf16* wto = (bf16*)(ws + WT_O);
  bf16* w1t = (bf16*)(ws + W1T);
  bf16* w2t = (bf16*)(ws + W2T);
  bf16* wht = (bf16*)(ws + WHT);
  float* em = (float*)(ws + EMOFF);
  float* ehm = (float*)(ws + EHOFF);
  bf16* hb = (bf16*)(ws + HB);
  bf16* qkvb = (bf16*)(ws + CQKV);                          // bf16 QKV intermediate (33 MB)
  bf16* ffb = (bf16*)(ws + CQKV);  // alias: qkv dead before FFN
  bf16* parto = (bf16*)(ws + CQKV);                         // 1320*5*2048 bf16 = 27 MB
  float* partml = (float*)(ws + CQKV + (size_t)1320 * 5 * 2048 * 2);  // 0.85 MB
  bf16* qbp = (bf16*)(ws + DQB);
  bf16* kbp = qbp + (size_t)NH * S_TOK * HD;
  bf16* vcp = kbp + (size_t)NH * S_TOK * HD;                // chunked V: 12*4*28*4096 el = 10.5 MB
  float* xf3 = (float*)(ws + DQB);  // alias: q/k/vc dead after attention
  bf16* attb = (bf16*)(ws + EATT);
  float* xf2 = (float*)(ws + GXF2);
  float* cstab = (float*)(ws + TRIG);

  k_prep<<<(NFRM * 8 * DIM) / 256, 256, 0, stream>>>(e, e_head, mod_block, mod_head, em, ehm);
  k_trig<<<(S_TOK * 64) / 256, 256, 0, stream>>>(ang, cstab);
  k_zero_vpad<<<NH * NFRM, 256, 0, stream>>>(vcp);

  k_transpose<<<dim3(48, 48), 256, 0, stream>>>(Wq, wtqkv, DIM, DIM);
  k_transpose<<<dim3(48, 48), 256, 0, stream>>>(Wk, wtqkv + (size_t)DIM * DIM, DIM, DIM);
  k_transpose<<<dim3(48, 48), 256, 0, stream>>>(Wv, wtqkv + (size_t)2 * DIM * DIM, DIM, DIM);
  k_transpose<<<dim3(48, 48), 256, 0, stream>>>(Wo, wto, DIM, DIM);
  k_transpose<<<dim3(192, 48), 256, 0, stream>>>(W1, w1t, DIM, FFN_D);
  k_transpose<<<dim3(48, 192), 256, 0, stream>>>(W2, w2t, FFN_D, DIM);
  k_transpose<<<dim3(2, 48), 256, 0, stream>>>(Wh, wht, DIM, NOUT);
  hipMemsetAsync(ws + WHT + (size_t)NOUT * DIM * 2, 0, (size_t)(128 - NOUT) * DIM * 2, stream);
  hipMemsetAsync(ws + EATT + (size_t)S_TOK * DIM * 2, 0, (size_t)(S_PAD - S_TOK) * DIM * 2, stream);

  // AdaLN 1: h = LN(x)*(1+e1)+e0
  k_adaln<<<S_PAD, 256, 0, stream>>>(x, hb, em, em + DIM, 6 * DIM);

  // QKV fused GEMM -> bf16
  GemmP g0{};
  g0.A = hb; g0.Bt = wtqkv; g0.K = DIM; g0.Mtiles = 28; g0.Ntiles = 36; g0.Mreal = S_TOK;
  g0.mode = 0; g0.bias0 = bq; g0.bias1 = bk; g0.bias2 = bv; g0.outb = qkvb; g0.ldo = 3 * DIM;
  k_gemm<<<28 * 36, 512, 0, stream>>>(g0);

  k_qkv_post<<<S_TOK, 256, 0, stream>>>(qkvb, wqn, wkn, cstab, qbp, kbp, vcp);

  // split-KV attention: 1320 uniform blocks + reduce
  k_attn<<<NH * 110, 320, 0, stream>>>(qbp, kbp, vcp, parto, partml);
  k_att_reduce<<<NH * 44, 256, 0, stream>>>(parto, partml, attb);

  // O-proj + residual + e2 modulation -> xf2
  GemmP g1{};
  g1.A = attb; g1.Bt = wto; g1.K = DIM; g1.Mtiles = 28; g1.Ntiles = 12; g1.Mreal = S_TOK;
  g1.mode = 1; g1.bias0 = bo; g1.res = x; g1.emod = em + 2 * DIM; g1.e_fstride = 6 * DIM;
  g1.outf = xf2; g1.ldo = DIM;
  k_gemm<<<28 * 12, 512, 0, stream>>>(g1);

  // AdaLN 2
  k_adaln<<<S_PAD, 256, 0, stream>>>(xf2, hb, em + 3 * DIM, em + 4 * DIM, 6 * DIM);

  // FFN up + GELU -> bf16
  GemmP g2{};
  g2.A = hb; g2.Bt = w1t; g2.K = DIM; g2.Mtiles = 28; g2.Ntiles = 48; g2.Mreal = S_TOK;
  g2.mode = 2; g2.bias0 = b1; g2.outb = ffb; g2.ldo = FFN_D;
  k_gemm<<<28 * 48, 512, 0, stream>>>(g2);
  hipMemsetAsync(ws + CQKV + (size_t)S_TOK * FFN_D * 2, 0, (size_t)(S_PAD - S_TOK) * FFN_D * 2, stream);

  // FFN down + residual + e5 -> xf3
  GemmP g3{};
  g3.A = ffb; g3.Bt = w2t; g3.K = FFN_D; g3.Mtiles = 28; g3.Ntiles = 12; g3.Mreal = S_TOK;
  g3.mode = 1; g3.bias0 = b2; g3.res = xf2; g3.emod = em + 5 * DIM; g3.e_fstride = 6 * DIM;
  g3.outf = xf3; g3.ldo = DIM;
  k_gemm<<<28 * 12, 512, 0, stream>>>(g3);

  // Head AdaLN
  k_adaln<<<S_PAD, 256, 0, stream>>>(xf3, hb, ehm, ehm + DIM, 2 * DIM);

  // Head GEMM (N padded 64->128, stores guarded)
  GemmP g4{};
  g4.A = hb; g4.Bt = wht; g4.K = DIM; g4.Mtiles = 28; g4.Ntiles = 1; g4.Mreal = S_TOK;
  g4.mode = 4; g4.bias0 = bh; g4.outf = out; g4.ldo = NOUT;
  k_gemm<<<28, 512, 0, stream>>>(g4);
}

// Round 18
// 656.505 us; speedup vs baseline: 1.0014x; 1.0014x over previous
//
#include <hip/hip_runtime.h>
#include <cstdint>
#include <cstddef>

typedef __bf16 bf16;
typedef __bf16 bf16x2 __attribute__((ext_vector_type(2)));
typedef __bf16 bf16x4 __attribute__((ext_vector_type(4)));
typedef __bf16 bf16x8 __attribute__((ext_vector_type(8)));
typedef float f32x4 __attribute__((ext_vector_type(4)));
typedef unsigned int u32x4 __attribute__((ext_vector_type(4)));

#define S_TOK 3520
#define S_PAD 3584
#define P_TOK 880
#define NFRM 4
#define DIM 1536
#define NH 12
#define HD 128
#define FFN_D 6144
#define NOUT 64
#define EPSV 1e-6f
#define QSCALE 0.12751743f   /* log2(e)/sqrt(128) */

__device__ __forceinline__ f32x4 mfma16(bf16x8 a, bf16x8 b, f32x4 c) {
  return __builtin_amdgcn_mfma_f32_16x16x32_bf16(a, b, c, 0, 0, 0);
}

__device__ __forceinline__ void gload_lds16(const bf16* g, bf16* l) {
  __builtin_amdgcn_global_load_lds(
      (const __attribute__((address_space(1))) unsigned int*)g,
      (__attribute__((address_space(3))) unsigned int*)l, 16, 0, 0);
}

__device__ __forceinline__ uint32_t pk2(float lo, float hi) {
  bf16x2 t;
  t[0] = (bf16)lo;
  t[1] = (bf16)hi;
  return __builtin_bit_cast(uint32_t, t);
}

// ---------------- prep: em = mod_block + e ; ehm = mod_head + e_head ----------------
__global__ __launch_bounds__(256) void k_prep(const float* __restrict__ e,
                                              const float* __restrict__ e_head,
                                              const float* __restrict__ mod_block,
                                              const float* __restrict__ mod_head,
                                              float* __restrict__ em,
                                              float* __restrict__ ehm) {
  int i = blockIdx.x * 256 + threadIdx.x;
  if (i < NFRM * 6 * DIM) em[i] = mod_block[i % (6 * DIM)] + e[i];
  int j = i - NFRM * 6 * DIM;
  if (j >= 0 && j < NFRM * 2 * DIM) ehm[j] = mod_head[j % (2 * DIM)] + e_head[j];
}

// ---------------- trig table: cstab[s*64+c] = {cos, sin}(ang[s][c]) ----------------
__global__ __launch_bounds__(256) void k_trig(const float* __restrict__ ang,
                                              float* __restrict__ cstab) {
  int idx = blockIdx.x * 256 + threadIdx.x;
  float a = ang[idx];
  float sa, ca;
  sincosf(a, &sa, &ca);
  cstab[2 * idx] = ca;
  cstab[2 * idx + 1] = sa;
}

// ---------------- zero the V-chunk frame-tail pad (lb=27, slots 256..511) ----------------
__global__ __launch_bounds__(256) void k_zero_vpad(bf16* __restrict__ vc) {
  size_t base = ((size_t)blockIdx.x * 28 + 27) * 4096 + 2048 + (size_t)threadIdx.x * 8;
#pragma unroll
  for (int i = 0; i < 8; ++i) vc[base + i] = (bf16)0.f;
}

// ---------------- transpose f32 [K][N] -> bf16 [N][K] ----------------
__global__ __launch_bounds__(256) void k_transpose(const float* __restrict__ W,
                                                   bf16* __restrict__ Wt, int K, int N) {
  __shared__ float tile[32][33];
  int n0 = blockIdx.x * 32, k0 = blockIdx.y * 32;
  int tx = threadIdx.x & 31, ty = threadIdx.x >> 5;
#pragma unroll
  for (int j = 0; j < 4; ++j) {
    int k = k0 + ty * 4 + j;
    float v = (n0 + tx < N) ? W[(size_t)k * N + n0 + tx] : 0.f;
    tile[ty * 4 + j][tx] = v;
  }
  __syncthreads();
#pragma unroll
  for (int j = 0; j < 4; ++j) {
    int n = n0 + ty * 4 + j;
    if (n < N) Wt[(size_t)n * K + k0 + tx] = (bf16)tile[tx][ty * 4 + j];
  }
}

// ---------------- AdaLN (templated input dtype): out = LN(in)*(1+scale[f]) + shift[f] ----------------
template <typename T>
__global__ __launch_bounds__(256) void k_adaln(const T* __restrict__ in,
                                               bf16* __restrict__ out,
                                               const float* __restrict__ e_shift,
                                               const float* __restrict__ e_scale,
                                               int fstride) {
  int tok = blockIdx.x;
  int t = threadIdx.x;
  bf16* orow = out + (size_t)tok * DIM;
  if (tok >= S_TOK) {
#pragma unroll
    for (int i = 0; i < 6; ++i) orow[t * 6 + i] = (bf16)0.f;
    return;
  }
  const T* xrow = in + (size_t)tok * DIM;
  float v[6];
  float s = 0.f, sq = 0.f;
#pragma unroll
  for (int i = 0; i < 6; ++i) {
    v[i] = (float)xrow[t * 6 + i];
    s += v[i];
    sq += v[i] * v[i];
  }
  for (int off = 32; off; off >>= 1) {
    s += __shfl_down(s, off);
    sq += __shfl_down(sq, off);
  }
  __shared__ float red[8];
  int wv = t >> 6, lane = t & 63;
  if (lane == 0) { red[wv] = s; red[4 + wv] = sq; }
  __syncthreads();
  float ts = red[0] + red[1] + red[2] + red[3];
  float tq = red[4] + red[5] + red[6] + red[7];
  float mean = ts * (1.f / DIM);
  float var = tq * (1.f / DIM) - mean * mean;
  float rstd = rsqrtf(var + EPSV);
  int f = tok / P_TOK;
  const float* sh = e_shift + (size_t)f * fstride;
  const float* sc = e_scale + (size_t)f * fstride;
#pragma unroll
  for (int i = 0; i < 6; ++i) {
    int d = t * 6 + i;
    orow[d] = (bf16)((v[i] - mean) * rstd * (1.f + sc[d]) + sh[d]);
  }
}

// ---------------- QKV postproc (bf16 in): RMSNorm(q,k) + RoPE (table), scale q; v -> chunked ----------------
__global__ __launch_bounds__(256) void k_qkv_post(const bf16* __restrict__ qkv,
                                                  const float* __restrict__ wqn,
                                                  const float* __restrict__ wkn,
                                                  const float* __restrict__ cstab,
                                                  bf16* __restrict__ qb,
                                                  bf16* __restrict__ kb,
                                                  bf16* __restrict__ vc) {
  int s = blockIdx.x;
  int t = threadIdx.x;
  const bf16* row = qkv + (size_t)s * 3 * DIM;
  float qv[6], kv[6], vv[6];
  float sqq = 0.f, sqk = 0.f;
  int d0 = t * 6;
#pragma unroll
  for (int i = 0; i < 6; ++i) {
    int d = d0 + i;
    qv[i] = (float)row[d];
    kv[i] = (float)row[DIM + d];
    vv[i] = (float)row[2 * DIM + d];
    sqq += qv[i] * qv[i];
    sqk += kv[i] * kv[i];
  }
  float a1 = sqq, a2 = sqk;
  for (int off = 32; off; off >>= 1) {
    a1 += __shfl_down(a1, off);
    a2 += __shfl_down(a2, off);
  }
  __shared__ float red[8];
  int wv = t >> 6, lane = t & 63;
  if (lane == 0) { red[wv] = a1; red[4 + wv] = a2; }
  __syncthreads();
  float tq = red[0] + red[1] + red[2] + red[3];
  float tk = red[4] + red[5] + red[6] + red[7];
  float rq = rsqrtf(tq * (1.f / DIM) + EPSV);
  float rk = rsqrtf(tk * (1.f / DIM) + EPSV);
  const float2* cs2 = (const float2*)cstab + (size_t)s * 64;
#pragma unroll
  for (int p = 0; p < 3; ++p) {
    int d = d0 + p * 2;
    int h = d >> 7;
    int hd = d & 127;
    int c = hd >> 1;
    float2 cs = cs2[c];
    float ca = cs.x, sa = cs.y;
    float q0 = qv[p * 2] * rq * wqn[d], q1 = qv[p * 2 + 1] * rq * wqn[d + 1];
    float k0 = kv[p * 2] * rk * wkn[d], k1 = kv[p * 2 + 1] * rk * wkn[d + 1];
    size_t base = ((size_t)h * S_TOK + s) * HD + hd;
    qb[base]     = (bf16)((q0 * ca - q1 * sa) * QSCALE);
    qb[base + 1] = (bf16)((q0 * sa + q1 * ca) * QSCALE);
    kb[base]     = (bf16)(k0 * ca - k1 * sa);
    kb[base + 1] = (bf16)(k0 * sa + k1 * ca);
  }
  int f = s / P_TOK;
  int l = s - f * P_TOK;
  int lb = l >> 5, gg = (l >> 3) & 3, r = l & 7;
#pragma unroll
  for (int i = 0; i < 6; ++i) {
    int d = d0 + i;
    int h = d >> 7, hd = d & 127;
    vc[((((size_t)(h * NFRM + f)) * 28 + lb) * 512 + gg * 128 + hd) * 8 + r] = (bf16)vv[i];
  }
}

// ---------------- attention (split-KV partials), KVBLK=32, dbuf-K + single-buffer V (R17) ----------------
__global__ __launch_bounds__(320) void k_attn(const bf16* __restrict__ qb,
                                              const bf16* __restrict__ kb,
                                              const bf16* __restrict__ vc,
                                              bf16* __restrict__ parto,
                                              float* __restrict__ partml) {
  __shared__ __align__(16) bf16 Ks[2][512 * 8];
  __shared__ __align__(16) bf16 Vs[512 * 8];
  int h = blockIdx.x / 110;
  int p = blockIdx.x % 110;
  int f = (p < 11) ? 0 : (p < 33) ? 1 : (p < 66) ? 2 : 3;
  int cum = (f == 0) ? 0 : (f == 1) ? 11 : (f == 2) ? 33 : 66;
  int w = p - cum;
  int kc = w / 11;
  int qt = f * 11 + w % 11;
  int slot = blockIdx.x;
  int t = threadIdx.x;
  int wv = t >> 6, lane = t & 63;
  int r16 = lane & 15, g = lane >> 4;
  int q0 = qt * 80 + wv * 16;
  int kv0 = kc * P_TOK;
  const bf16* qbase = qb + ((size_t)h * S_TOK + q0 + r16) * HD + g * 8;
  bf16x8 qf[4];
#pragma unroll
  for (int kk = 0; kk < 4; ++kk) qf[kk] = *(const bf16x8*)(qbase + kk * 32);
  f32x4 acc[8] = {};
  float mrow = -1e30f, lrow = 0.f;
  int src01 = r16 + ((2 * g) & 3) * 16;
  int src23 = src01 + 16;
  bool glo = (g < 2);
  int sB = t + 256;
  int kr0 = t >> 4, kl0 = t & 15;
  int ks0 = (kl0 & 8) | ((kl0 ^ kr0) & 7);
  int kr1 = sB >> 4, kl1 = sB & 15;
  int ks1 = (kl1 & 8) | ((kl1 ^ kr1) & 7);
  const bf16* kh = kb + (size_t)h * S_TOK * HD;
  const bf16* vchunk = vc + ((size_t)(h * NFRM + kc)) * 28 * 4096;
#define STAGE_K(buf, jj)                                                    \
  do {                                                                      \
    int kvoj = (jj) * 32;                                                   \
    int gr0 = kv0 + kvoj + kr0; if (gr0 >= S_TOK) gr0 = 0;                  \
    int gr1 = kv0 + kvoj + kr1; if (gr1 >= S_TOK) gr1 = 0;                  \
    gload_lds16(kh + (size_t)gr0 * HD + ks0 * 8, Ks[buf] + t * 8);          \
    gload_lds16(kh + (size_t)gr1 * HD + ks1 * 8, Ks[buf] + sB * 8);         \
  } while (0)
#define STAGE_V(jj)                                                         \
  do {                                                                      \
    gload_lds16(vchunk + (size_t)(jj) * 4096 + t * 8, Vs + t * 8);          \
    gload_lds16(vchunk + (size_t)(jj) * 4096 + sB * 8, Vs + sB * 8);        \
  } while (0)
  const int nsteps = (P_TOK + 31) >> 5;
  if (t < 256) STAGE_K(0, 0);
  int vrb = g * 128 + r16;
  for (int j = 0; j < nsteps; ++j) {
    if (t < 256) STAGE_V(j);
    if (j + 1 < nsteps) {
      if (t < 256) STAGE_K((j + 1) & 1, j + 1);
      asm volatile("s_waitcnt vmcnt(4)" ::: "memory");
    } else {
      asm volatile("s_waitcnt vmcnt(0)" ::: "memory");
    }
    __builtin_amdgcn_s_barrier();
    const bf16* Kc = Ks[j & 1];
    f32x4 st0 = {0.f, 0.f, 0.f, 0.f}, st1 = {0.f, 0.f, 0.f, 0.f};
#pragma unroll
    for (int kk = 0; kk < 4; ++kk) {
      int sl = g + 4 * kk;
      int ss = (sl & 8) | ((sl ^ r16) & 7);
      bf16x8 k0 = *(const bf16x8*)(Kc + (r16 * 16 + ss) * 8);
      bf16x8 k1 = *(const bf16x8*)(Kc + ((16 + r16) * 16 + ss) * 8);
      st0 = mfma16(k0, qf[kk], st0);
      st1 = mfma16(k1, qf[kk], st1);
    }
    float hm = (j == nsteps - 1) ? -1e30f : 0.f;
    float a0[4], a1[4];
#pragma unroll
    for (int r = 0; r < 4; ++r) {
      a0[r] = st0[r];
      a1[r] = st1[r] + hm;
    }
    float tm = fmaxf(fmaxf(fmaxf(a0[0], a0[1]), fmaxf(a0[2], a0[3])),
                     fmaxf(fmaxf(a1[0], a1[1]), fmaxf(a1[2], a1[3])));
    tm = fmaxf(tm, __shfl_xor(tm, 16));
    tm = fmaxf(tm, __shfl_xor(tm, 32));
    bool defer = __all(tm <= mrow + 8.f);
    if (!defer) {
      float mn = fmaxf(mrow, tm);
      float scl = exp2f(mrow - mn);
      lrow *= scl;
#pragma unroll
      for (int hb = 0; hb < 8; ++hb) {
        acc[hb][0] *= scl;
        acc[hb][1] *= scl;
        acc[hb][2] *= scl;
        acc[hb][3] *= scl;
      }
      mrow = mn;
    }
    float p0[4], p1[4], ps = 0.f;
#pragma unroll
    for (int r = 0; r < 4; ++r) {
      p0[r] = exp2f(a0[r] - mrow);
      p1[r] = exp2f(a1[r] - mrow);
      ps += p0[r] + p1[r];
    }
    lrow += ps;
    uint32_t A0 = pk2(p0[0], p0[1]), A1 = pk2(p0[2], p0[3]);
    uint32_t B0 = pk2(p1[0], p1[1]), B1 = pk2(p1[2], p1[3]);
    uint32_t sA0 = __shfl(A0, src01), sA1 = __shfl(A1, src01);
    uint32_t sB0 = __shfl(B0, src01), sB1 = __shfl(B1, src01);
    uint32_t tA0 = __shfl(A0, src23), tA1 = __shfl(A1, src23);
    uint32_t tB0 = __shfl(B0, src23), tB1 = __shfl(B1, src23);
    u32x4 wds;
    wds[0] = glo ? sA0 : sB0;
    wds[1] = glo ? sA1 : sB1;
    wds[2] = glo ? tA0 : tB0;
    wds[3] = glo ? tA1 : tB1;
    bf16x8 pb = __builtin_bit_cast(bf16x8, wds);
    const bf16* vsl = Vs + (size_t)vrb * 8;
#pragma unroll
    for (int hb = 0; hb < 8; ++hb) {
      bf16x8 vfr = *(const bf16x8*)(vsl + hb * 128);
      acc[hb] = mfma16(vfr, pb, acc[hb]);
    }
    asm volatile("" ::: "memory");
    __builtin_amdgcn_s_barrier();
  }
#undef STAGE_K
#undef STAGE_V
  lrow += __shfl_xor(lrow, 16);
  lrow += __shfl_xor(lrow, 32);
  bf16* obase = parto + ((size_t)slot * 5 + wv) * 2048;
#pragma unroll
  for (int hb = 0; hb < 8; ++hb) {
    bf16x4 ov;
    ov[0] = (bf16)acc[hb][0];
    ov[1] = (bf16)acc[hb][1];
    ov[2] = (bf16)acc[hb][2];
    ov[3] = (bf16)acc[hb][3];
    *(bf16x4*)(obase + (hb * 64 + lane) * 4) = ov;
  }
  if (g == 0) {
    float* mlb = partml + ((size_t)slot * 5 + wv) * 32;
    mlb[r16] = mrow;
    mlb[16 + r16] = lrow;
  }
}

// ---------------- attention reduce: combine <=4 frame-chunk partials per q-row ----------------
__global__ __launch_bounds__(256) void k_att_reduce(const bf16* __restrict__ parto,
                                                    const float* __restrict__ partml,
                                                    bf16* __restrict__ attb) {
  int b = blockIdx.x;
  int h = b / 44, qt = b % 44;
  int f = qt / 11, j = qt % 11;
  int cum = (f == 0) ? 0 : (f == 1) ? 11 : (f == 2) ? 33 : 66;
  int t = threadIdx.x;
  int d = t & 127, half = t >> 7;
  int hb = d >> 4, g = (d >> 2) & 3, r = d & 3;
  int q0 = qt * 80;
  for (int it = 0; it < 40; ++it) {
    int qloc = it + 40 * half;
    int wv = qloc >> 4, r16 = qloc & 15;
    float m[4], l[4];
    float mt = -1e30f;
    for (int kc = 0; kc <= f; ++kc) {
      int slot = h * 110 + cum + kc * 11 + j;
      const float* mlb = partml + ((size_t)slot * 5 + wv) * 32;
      m[kc] = mlb[r16];
      l[kc] = mlb[16 + r16];
      mt = fmaxf(mt, m[kc]);
    }
    float lt = 0.f, o = 0.f;
    for (int kc = 0; kc <= f; ++kc) {
      int slot = h * 110 + cum + kc * 11 + j;
      float wgt = exp2f(m[kc] - mt);
      lt += l[kc] * wgt;
      o += (float)parto[(((size_t)slot * 5 + wv) * 8 + hb) * 256 + (g * 16 + r16) * 4 + r] * wgt;
    }
    attb[(size_t)(q0 + qloc) * DIM + h * HD + d] = (bf16)(o / lt);
  }
}

// ---------------- unified 128x128 BK=64 GEMM (R14 structure): bf16 residual stream ----------------
struct GemmP {
  const bf16* A;
  const bf16* Bt;
  int K;
  int Mtiles;
  int Ntiles;
  int Mreal;
  int mode;  // 0: qkv bias3 -> bf16  1: resf/resb + (acc+b)*emod -> bf16  2: gelu->bf16  4: head f32 (col<64)
  const float* bias0;
  const float* bias1;
  const float* bias2;
  const float* resf;   // f32 residual (g1)
  const bf16* resb;    // bf16 residual (g3)
  const float* emod;
  int e_fstride;
  float* outf;
  bf16* outb;
  int ldo;
};

__global__ __launch_bounds__(512, 4) void k_gemm(GemmP p) {
  int nwg = p.Mtiles * p.Ntiles;
  int bid = blockIdx.x;
  int xq = nwg >> 3, xr = nwg & 7;
  int xcd = bid & 7, jj = bid >> 3;
  int wg = (xcd < xr ? xcd * (xq + 1) : xr * (xq + 1) + (xcd - xr) * xq) + jj;
  int bm = wg % p.Mtiles;
  int bn = wg / p.Mtiles;
  __shared__ __align__(16) bf16 Asl[2][128 * 64];
  __shared__ __align__(16) bf16 Bsl[2][128 * 64];
  int t = threadIdx.x, lane = t & 63, wv = t >> 6;
  int r16 = lane & 15, g = lane >> 4;
  int s7 = r16 & 7;
  int wr = wv >> 2, wc = wv & 3;
  f32x4 acc[4][2] = {};
  const bf16* Ag = p.A + (size_t)bm * 128 * p.K;
  const bf16* Bg = p.Bt + (size_t)bn * 128 * p.K;
  int b0 = t, b1 = t + 512;
  int rw0 = b0 >> 3, cb0 = (b0 & 7) ^ (rw0 & 7);
  int rw1 = b1 >> 3, cb1 = (b1 & 7) ^ (rw1 & 7);
#define STAGE(d, kt)                                                          \
  do {                                                                        \
    int k0s = (kt) * 64;                                                      \
    gload_lds16(Ag + (size_t)rw0 * p.K + k0s + cb0 * 8, Asl[d] + b0 * 8);     \
    gload_lds16(Ag + (size_t)rw1 * p.K + k0s + cb1 * 8, Asl[d] + b1 * 8);     \
    gload_lds16(Bg + (size_t)rw0 * p.K + k0s + cb0 * 8, Bsl[d] + b0 * 8);     \
    gload_lds16(Bg + (size_t)rw1 * p.K + k0s + cb1 * 8, Bsl[d] + b1 * 8);     \
  } while (0)
  const int nt = p.K >> 6;
  STAGE(0, 0);
  int cur = 0;
  for (int tt = 0; tt < nt; ++tt) {
    if (tt + 1 < nt) {
      STAGE(cur ^ 1, tt + 1);
      asm volatile("s_waitcnt vmcnt(4)" ::: "memory");
    } else {
      asm volatile("s_waitcnt vmcnt(0)" ::: "memory");
    }
    __builtin_amdgcn_s_barrier();
    bf16x8 af[4][2], bfr[2][2];
#pragma unroll
    for (int mi = 0; mi < 4; ++mi)
#pragma unroll
      for (int kk = 0; kk < 2; ++kk)
        af[mi][kk] = *(const bf16x8*)(Asl[cur] + (size_t)(wr * 64 + mi * 16 + r16) * 64 +
                                      (((kk * 4 + g) ^ s7) * 8));
#pragma unroll
    for (int ni = 0; ni < 2; ++ni)
#pragma unroll
      for (int kk = 0; kk < 2; ++kk)
        bfr[ni][kk] = *(const bf16x8*)(Bsl[cur] + (size_t)(wc * 32 + ni * 16 + r16) * 64 +
                                       (((kk * 4 + g) ^ s7) * 8));
    __builtin_amdgcn_s_setprio(1);
#pragma unroll
    for (int mi = 0; mi < 4; ++mi)
#pragma unroll
      for (int ni = 0; ni < 2; ++ni)
#pragma unroll
        for (int kk = 0; kk < 2; ++kk)
          acc[mi][ni] = mfma16(af[mi][kk], bfr[ni][kk], acc[mi][ni]);
    __builtin_amdgcn_s_setprio(0);
    asm volatile("" ::: "memory");
    __builtin_amdgcn_s_barrier();
    cur ^= 1;
  }
#undef STAGE
  int mbase = bm * 128 + wr * 64, nbase = bn * 128 + wc * 32;
#pragma unroll
  for (int mi = 0; mi < 4; ++mi) {
#pragma unroll
    for (int ni = 0; ni < 2; ++ni) {
      int col = nbase + ni * 16 + r16;
#pragma unroll
      for (int r = 0; r < 4; ++r) {
        int row = mbase + mi * 16 + 4 * g + r;
        if (row >= p.Mreal) continue;
        float v = acc[mi][ni][r];
        if (p.mode == 0) {
          float b = col < DIM ? p.bias0[col]
                              : (col < 2 * DIM ? p.bias1[col - DIM] : p.bias2[col - 2 * DIM]);
          p.outb[(size_t)row * p.ldo + col] = (bf16)(v + b);
        } else if (p.mode == 1) {
          int fr = row / P_TOK;
          float rv = p.resf ? p.resf[(size_t)row * DIM + col]
                            : (float)p.resb[(size_t)row * DIM + col];
          p.outb[(size_t)row * p.ldo + col] =
              (bf16)(rv + (v + p.bias0[col]) * p.emod[(size_t)fr * p.e_fstride + col]);
        } else if (p.mode == 2) {
          float xg = v + p.bias0[col];
          float gl = 0.5f * xg * (1.f + tanhf(0.7978845608028654f * (xg + 0.044715f * xg * xg * xg)));
          p.outb[(size_t)row * p.ldo + col] = (bf16)gl;
        } else {  // mode 4
          if (col < NOUT) p.outf[(size_t)row * p.ldo + col] = v + p.bias0[col];
        }
      }
    }
  }
}

extern "C" void kernel_launch(void* const* d_in, const int* in_sizes, int n_in,
                              void* d_out, int out_size, void* d_ws, size_t ws_size,
                              hipStream_t stream) {
  const float* x = (const float*)d_in[0];
  const float* e = (const float*)d_in[1];
  const float* e_head = (const float*)d_in[2];
  const float* ang = (const float*)d_in[3];
  const float* mod_block = (const float*)d_in[4];
  const float* mod_head = (const float*)d_in[5];
  const float* Wq = (const float*)d_in[6];
  const float* bq = (const float*)d_in[7];
  const float* Wk = (const float*)d_in[8];
  const float* bk = (const float*)d_in[9];
  const float* Wv = (const float*)d_in[10];
  const float* bv = (const float*)d_in[11];
  const float* Wo = (const float*)d_in[12];
  const float* bo = (const float*)d_in[13];
  const float* wqn = (const float*)d_in[14];
  const float* wkn = (const float*)d_in[15];
  const float* W1 = (const float*)d_in[16];
  const float* b1 = (const float*)d_in[17];
  const float* W2 = (const float*)d_in[18];
  const float* b2 = (const float*)d_in[19];
  const float* Wh = (const float*)d_in[20];
  const float* bh = (const float*)d_in[21];
  float* out = (float*)d_out;
  char* ws = (char*)d_ws;

  size_t WT_QKV = 0;
  size_t WT_O = WT_QKV + (size_t)3 * DIM * DIM * 2;
  size_t W1T = WT_O + (size_t)DIM * DIM * 2;
  size_t W2T = W1T + (size_t)FFN_D * DIM * 2;
  size_t WHT = W2T + (size_t)DIM * FFN_D * 2;
  size_t EMOFF = WHT + (size_t)128 * DIM * 2;
  size_t EHOFF = EMOFF + (size_t)NFRM * 6 * DIM * 4;
  size_t HB = EHOFF + (size_t)NFRM * 2 * DIM * 4;
  size_t CQKV = HB + (size_t)S_PAD * DIM * 2;
  size_t DQB = CQKV + (size_t)S_TOK * 3 * DIM * 4;
  size_t EATT = DQB + (size_t)3 * NH * S_TOK * HD * 2;
  size_t GXF2 = EATT + (size_t)S_PAD * DIM * 2;
  size_t TRIG = GXF2 + (size_t)S_TOK * DIM * 4;
  size_t END = TRIG + (size_t)S_TOK * 64 * 2 * 4;
  if (ws_size < END) return;  // insufficient workspace: bail cleanly

  bf16* wtqkv = (bf16*)(ws + WT_QKV);
  bf16* wto = (bf16*)(ws + WT_O);
  bf16* w1t = (bf16*)(ws + W1T);
  bf16* w2t = (bf16*)(ws + W2T);
  bf16* wht = (bf16*)(ws + WHT);
  float* em = (float*)(ws + EMOFF);
  float* ehm = (float*)(ws + EHOFF);
  bf16* hb = (bf16*)(ws + HB);
  bf16* qkvb = (bf16*)(ws + CQKV);                          // bf16 QKV intermediate (33 MB)
  bf16* ffb = (bf16*)(ws + CQKV);  // alias: qkv dead before FFN
  bf16* parto = (bf16*)(ws + CQKV);                         // 1320*5*2048 bf16 = 27 MB
  float* partml = (float*)(ws + CQKV + (size_t)1320 * 5 * 2048 * 2);  // 0.85 MB
  bf16* qbp = (bf16*)(ws + DQB);
  bf16* kbp = qbp + (size_t)NH * S_TOK * HD;
  bf16* vcp = kbp + (size_t)NH * S_TOK * HD;                // chunked V: 10.5 MB
  bf16* xf3b = (bf16*)(ws + DQB);  // alias: q/k/vc dead after attention (bf16 now)
  bf16* attb = (bf16*)(ws + EATT);
  bf16* xf2b = (bf16*)(ws + GXF2);
  float* cstab = (float*)(ws + TRIG);

  k_prep<<<(NFRM * 8 * DIM) / 256, 256, 0, stream>>>(e, e_head, mod_block, mod_head, em, ehm);
  k_trig<<<(S_TOK * 64) / 256, 256, 0, stream>>>(ang, cstab);
  k_zero_vpad<<<NH * NFRM, 256, 0, stream>>>(vcp);

  k_transpose<<<dim3(48, 48), 256, 0, stream>>>(Wq, wtqkv, DIM, DIM);
  k_transpose<<<dim3(48, 48), 256, 0, stream>>>(Wk, wtqkv + (size_t)DIM * DIM, DIM, DIM);
  k_transpose<<<dim3(48, 48), 256, 0, stream>>>(Wv, wtqkv + (size_t)2 * DIM * DIM, DIM, DIM);
  k_transpose<<<dim3(48, 48), 256, 0, stream>>>(Wo, wto, DIM, DIM);
  k_transpose<<<dim3(192, 48), 256, 0, stream>>>(W1, w1t, DIM, FFN_D);
  k_transpose<<<dim3(48, 192), 256, 0, stream>>>(W2, w2t, FFN_D, DIM);
  k_transpose<<<dim3(2, 48), 256, 0, stream>>>(Wh, wht, DIM, NOUT);
  hipMemsetAsync(ws + WHT + (size_t)NOUT * DIM * 2, 0, (size_t)(128 - NOUT) * DIM * 2, stream);
  hipMemsetAsync(ws + EATT + (size_t)S_TOK * DIM * 2, 0, (size_t)(S_PAD - S_TOK) * DIM * 2, stream);

  // AdaLN 1: h = LN(x)*(1+e1)+e0   (f32 input)
  k_adaln<float><<<S_PAD, 256, 0, stream>>>(x, hb, em, em + DIM, 6 * DIM);

  // QKV fused GEMM -> bf16
  GemmP g0{};
  g0.A = hb; g0.Bt = wtqkv; g0.K = DIM; g0.Mtiles = 28; g0.Ntiles = 36; g0.Mreal = S_TOK;
  g0.mode = 0; g0.bias0 = bq; g0.bias1 = bk; g0.bias2 = bv; g0.outb = qkvb; g0.ldo = 3 * DIM;
  k_gemm<<<28 * 36, 512, 0, stream>>>(g0);

  k_qkv_post<<<S_TOK, 256, 0, stream>>>(qkvb, wqn, wkn, cstab, qbp, kbp, vcp);

  // split-KV attention: 1320 uniform blocks + reduce
  k_attn<<<NH * 110, 320, 0, stream>>>(qbp, kbp, vcp, parto, partml);
  k_att_reduce<<<NH * 44, 256, 0, stream>>>(parto, partml, attb);

  // O-proj + residual(x, f32) + e2 modulation -> xf2 (bf16)
  GemmP g1{};
  g1.A = attb; g1.Bt = wto; g1.K = DIM; g1.Mtiles = 28; g1.Ntiles = 12; g1.Mreal = S_TOK;
  g1.mode = 1; g1.bias0 = bo; g1.resf = x; g1.emod = em + 2 * DIM; g1.e_fstride = 6 * DIM;
  g1.outb = xf2b; g1.ldo = DIM;
  k_gemm<<<28 * 12, 512, 0, stream>>>(g1);

  // AdaLN 2 (bf16 input)
  k_adaln<bf16><<<S_PAD, 256, 0, stream>>>(xf2b, hb, em + 3 * DIM, em + 4 * DIM, 6 * DIM);

  // FFN up + GELU -> bf16
  GemmP g2{};
  g2.A = hb; g2.Bt = w1t; g2.K = DIM; g2.Mtiles = 28; g2.Ntiles = 48; g2.Mreal = S_TOK;
  g2.mode = 2; g2.bias0 = b1; g2.outb = ffb; g2.ldo = FFN_D;
  k_gemm<<<28 * 48, 512, 0, stream>>>(g2);
  hipMemsetAsync(ws + CQKV + (size_t)S_TOK * FFN_D * 2, 0, (size_t)(S_PAD - S_TOK) * FFN_D * 2, stream);

  // FFN down + residual(xf2, bf16) + e5 -> xf3 (bf16)
  GemmP g3{};
  g3.A = ffb; g3.Bt = w2t; g3.K = FFN_D; g3.Mtiles = 28; g3.Ntiles = 12; g3.Mreal = S_TOK;
  g3.mode = 1; g3.bias0 = b2; g3.resb = xf2b; g3.emod = em + 5 * DIM; g3.e_fstride = 6 * DIM;
  g3.outb = xf3b; g3.ldo = DIM;
  k_gemm<<<28 * 12, 512, 0, stream>>>(g3);

  // Head AdaLN (bf16 input)
  k_adaln<bf16><<<S_PAD, 256, 0, stream>>>(xf3b, hb, ehm, ehm + DIM, 2 * DIM);

  // Head GEMM (N padded 64->128, stores guarded)
  GemmP g4{};
  g4.A = hb; g4.Bt = wht; g4.K = DIM; g4.Mtiles = 28; g4.Ntiles = 1; g4.Mreal = S_TOK;
  g4.mode = 4; g4.bias0 = bh; g4.outf = out; g4.ldo = NOUT;
  k_gemm<<<28, 512, 0, stream>>>(g4);
}